// Round 16
// baseline (97.859 us; speedup 1.0000x reference)
//
#include <hip/hip_runtime.h>
#include <hip/hip_bf16.h>

#define SEQL  2048
#define NHQ   32
#define NHKV  8
#define HD    128

typedef __attribute__((ext_vector_type(4)))  float          f32x4;
typedef __attribute__((ext_vector_type(16))) float          f32x16;
typedef __attribute__((ext_vector_type(8)))  short          bf16x8;
typedef __attribute__((ext_vector_type(4)))  unsigned short u16x4;
typedef __attribute__((ext_vector_type(8)))  unsigned short u16x8;

__device__ __forceinline__ unsigned short f2bf(float f) {
  union { float f; unsigned u; } v; v.f = f;
  unsigned u = v.u;
  return (unsigned short)((u + 0x7fffu + ((u >> 16) & 1u)) >> 16);
}

__device__ __forceinline__ unsigned cvtpk_bf16(float lo, float hi) {
  unsigned r;
  asm("v_cvt_pk_bf16_f32 %0, %1, %2" : "=v"(r) : "v"(lo), "v"(hi));
  return r;
}

__device__ __forceinline__ void gload16(const void* g, void* l) {
  __builtin_amdgcn_global_load_lds(
      (const __attribute__((address_space(1))) unsigned int*)g,
      (__attribute__((address_space(3))) unsigned int*)l, 16, 0, 0);
}

// ---------------- prepass (verified R2-R15) ----------------
// ws K layout: [hkv][kvtile(32)][8192 halfwords], element (r,d) at (r*128+d)^((r&7)<<3)
__global__ __launch_bounds__(256) void prep_k(const float* __restrict__ k,
                                              unsigned short* __restrict__ kws) {
  int t = blockIdx.x * 256 + threadIdx.x;
  int s   = t >> 7;
  int col = (t & 127) << 3;
  int hkv = col >> 7;
  int d0  = col & 127;
  const float* src = k + (size_t)s * (NHKV * HD) + col;
  f32x4 a = *(const f32x4*)src;
  f32x4 b = *(const f32x4*)(src + 4);
  u16x8 r;
  r[0] = f2bf(a[0]); r[1] = f2bf(a[1]); r[2] = f2bf(a[2]); r[3] = f2bf(a[3]);
  r[4] = f2bf(b[0]); r[5] = f2bf(b[1]); r[6] = f2bf(b[2]); r[7] = f2bf(b[3]);
  int tile = s >> 6, rr = s & 63;
  int idx = (rr * 128 + d0) ^ ((rr & 7) << 3);
  *(u16x8*)(kws + (((size_t)(hkv * 32 + tile)) << 13) + idx) = r;
}

// ws V layout for 32x32 zero-shuffle PV (verified R14/R15): slot (d,s,h,j) at
// (d*64 + s*16 + h*8 + j)^((d&7)<<3) holds V[tile*64 + 16s + 4h + 8*(j>>2) + (j&3)][d]
__global__ __launch_bounds__(256) void prep_v(const float* __restrict__ v,
                                              unsigned short* __restrict__ vws) {
  int t = blockIdx.x * 256 + threadIdx.x;
  int d    = t & 127;
  int hkv  = (t >> 7) & 7;
  int rest = t >> 10;
  int tile = rest >> 3;
  int s    = (rest >> 1) & 3;
  int hh   = rest & 1;
  int s0   = tile * 64 + s * 16 + hh * 4;
  const float* src = v + (size_t)s0 * (NHKV * HD) + hkv * HD + d;
  u16x8 r;
  #pragma unroll
  for (int j = 0; j < 8; ++j) {
    int soff = ((j >> 2) << 3) + (j & 3);
    r[j] = f2bf(src[(size_t)soff * (NHKV * HD)]);
  }
  int idx = (d * 64 + s * 16 + hh * 8) ^ ((d & 7) << 3);
  *(u16x8*)(vws + (((size_t)(hkv * 32 + tile)) << 13) + idx) = r;
}

// ---- main (v16): SIBLING-CHUNK blocks. Chunks 2k and 2k+1 share the same      ----
// ---- 128-row mask block -> IDENTICAL kv extent (k+1)*2 tiles. Block = 4 waves: ----
// ---- wv0,1 = halves of chunk 2k; wv2,3 = halves of chunk 2k+1. Every staged   ----
// ---- tile feeds all 4 waves for the whole block -> zero idle slots, zero      ----
// ---- wasted tiles (total staged rounds -32% vs R15).                          ----
// ---- bx layout: hkv=bx&7 (XCD affinity), k=(bx>>3)&15, hq=(bx>>7)&3: blocks   ----
// ---- bx and bx+256 (same CU, 512=2x256) share k -> both finish together,      ----
// ---- full 8-wave rounds on the wall-critical (k=15) CUs.                      ----
// LDS = 2x16K (K) + 2x16K (V) = 65536 B -> 2 blocks/CU.
__global__ __launch_bounds__(256, 2) void attn_fwd16(
    const float* __restrict__ q,
    const unsigned short* __restrict__ kws,
    const unsigned short* __restrict__ vws,
    float* __restrict__ out)
{
  __shared__ unsigned short Kb[2][8192];
  __shared__ unsigned short Vb[2][8192];

  const int tid  = threadIdx.x;
  const int lane = tid & 63;
  const int wv   = tid >> 6;           // 0..3
  const int l31  = lane & 31;
  const int h8   = lane >> 5;          // 0..1

  const int bx   = blockIdx.x;
  const int hkv  = bx & 7;             // XCD-affine kv head (bits 0-2)
  const int kk   = (bx >> 3) & 15;     // mask-block index (bits 3-6; same for bx, bx+256)
  const int hq   = (bx >> 7) & 3;      // query head within group (bits 7-8)
  const int h    = hkv * 4 + hq;
  const int qt   = 2 * kk + ((wv >> 1) & 1);  // wv0,1 -> chunk 2k; wv2,3 -> chunk 2k+1
  const int nT   = (kk + 1) * 2;       // identical kv extent for both sibling chunks

  const float qscale = 0.08838834764831845f * 1.4426950408889634f;
  const float THR = 11.5f;

  const unsigned short* ktiles = kws + (((size_t)hkv * 32) << 13);
  const unsigned short* vtiles = vws + (((size_t)hkv * 32) << 13);

  bf16x8 qf[8];
  f32x16 oacc[4];
  float mrun = -1e30f, lrun = 0.f;

  // ---- Q fragments: lane holds Q[q = qt*64 + (wv&1)*32 + l31][d = c*16 + h8*8 + j] ----
  {
    const float* qbase = q + (size_t)(qt * 64 + (wv & 1) * 32 + l31) * (NHQ * HD) + h * HD + h8 * 8;
    #pragma unroll
    for (int c = 0; c < 8; ++c) {
      f32x4 a = *(const f32x4*)(qbase + c * 16);
      f32x4 b = *(const f32x4*)(qbase + c * 16 + 4);
      bf16x8 r;
      r[0] = (short)f2bf(a[0] * qscale);
      r[1] = (short)f2bf(a[1] * qscale);
      r[2] = (short)f2bf(a[2] * qscale);
      r[3] = (short)f2bf(a[3] * qscale);
      r[4] = (short)f2bf(b[0] * qscale);
      r[5] = (short)f2bf(b[1] * qscale);
      r[6] = (short)f2bf(b[2] * qscale);
      r[7] = (short)f2bf(b[3] * qscale);
      qf[c] = r;
    }
  }
  #pragma unroll
  for (int i = 0; i < 4; ++i)
    oacc[i] = (f32x16){0.f,0.f,0.f,0.f,0.f,0.f,0.f,0.f,0.f,0.f,0.f,0.f,0.f,0.f,0.f,0.f};

  auto STAGE = [&](int b, int kvt) {
    const char* gk = (const char*)(ktiles + ((size_t)kvt << 13));
    const char* gv = (const char*)(vtiles + ((size_t)kvt << 13));
    char* lk = (char*)&Kb[b][0];
    char* lv = (char*)&Vb[b][0];
    #pragma unroll
    for (int i = 0; i < 4; ++i) {
      const int off = wv * 4096 + i * 1024;
      gload16(gk + off + lane * 16, lk + off);
      gload16(gv + off + lane * 16, lv + off);
    }
  };

  // ---- compute: byte-identical to R14/R15's numerics-verified body ----
  auto compute = [&](int b) {
    f32x16 s0 = (f32x16){0.f,0.f,0.f,0.f,0.f,0.f,0.f,0.f,0.f,0.f,0.f,0.f,0.f,0.f,0.f,0.f};
    f32x16 s1 = s0;
    __builtin_amdgcn_s_setprio(1);
    #pragma unroll
    for (int c = 0; c < 8; ++c) {
      const int r0 = l31;
      const int r1 = 32 + l31;
      bf16x8 kf0 = *(const bf16x8*)(&Kb[b][(r0 * 128 + c * 16 + h8 * 8) ^ ((r0 & 7) << 3)]);
      bf16x8 kf1 = *(const bf16x8*)(&Kb[b][(r1 * 128 + c * 16 + h8 * 8) ^ ((r1 & 7) << 3)]);
      s0 = __builtin_amdgcn_mfma_f32_32x32x16_bf16(kf0, qf[c], s0, 0, 0, 0);
      s1 = __builtin_amdgcn_mfma_f32_32x32x16_bf16(kf1, qf[c], s1, 0, 0, 0);
    }
    __builtin_amdgcn_s_setprio(0);
    float m0 = fmaxf(fmaxf(s0[0], s0[1]),  fmaxf(s0[2], s0[3]));
    float m1 = fmaxf(fmaxf(s0[4], s0[5]),  fmaxf(s0[6], s0[7]));
    float m2 = fmaxf(fmaxf(s0[8], s0[9]),  fmaxf(s0[10], s0[11]));
    float m3 = fmaxf(fmaxf(s0[12], s0[13]), fmaxf(s0[14], s0[15]));
    float m4 = fmaxf(fmaxf(s1[0], s1[1]),  fmaxf(s1[2], s1[3]));
    float m5 = fmaxf(fmaxf(s1[4], s1[5]),  fmaxf(s1[6], s1[7]));
    float m6 = fmaxf(fmaxf(s1[8], s1[9]),  fmaxf(s1[10], s1[11]));
    float m7 = fmaxf(fmaxf(s1[12], s1[13]), fmaxf(s1[14], s1[15]));
    float mt = fmaxf(fmaxf(fmaxf(m0, m1), fmaxf(m2, m3)),
                     fmaxf(fmaxf(m4, m5), fmaxf(m6, m7)));
    mt = fmaxf(mt, __shfl_xor(mt, 32));
    if (__any(mt > mrun + THR)) {
      float mn = fmaxf(mrun, mt);
      float c0 = exp2f(mrun - mn);
      mrun = mn; lrun *= c0;
      #pragma unroll
      for (int i = 0; i < 4; ++i) oacc[i] *= c0;
    }
    unsigned pw[16];
    float ts = 0.f;
    #pragma unroll
    for (int i = 0; i < 8; ++i) {
      float p0 = exp2f(s0[2 * i]     - mrun);
      float p1 = exp2f(s0[2 * i + 1] - mrun);
      ts += p0 + p1;
      pw[i] = cvtpk_bf16(p0, p1);
    }
    #pragma unroll
    for (int i = 0; i < 8; ++i) {
      float p0 = exp2f(s1[2 * i]     - mrun);
      float p1 = exp2f(s1[2 * i + 1] - mrun);
      ts += p0 + p1;
      pw[8 + i] = cvtpk_bf16(p0, p1);
    }
    ts += __shfl_xor(ts, 32);
    lrun += ts;
    __builtin_amdgcn_s_setprio(1);
    #pragma unroll
    for (int db = 0; db < 4; ++db) {
      const int d = db * 32 + l31;
      f32x16 acc = oacc[db];
      #pragma unroll
      for (int s = 0; s < 4; ++s) {
        bf16x8 vf = *(const bf16x8*)(&Vb[b][(d * 64 + s * 16 + h8 * 8) ^ ((d & 7) << 3)]);
        union { unsigned u[4]; bf16x8 v8; } pk;
        pk.u[0] = pw[4 * s + 0];
        pk.u[1] = pw[4 * s + 1];
        pk.u[2] = pw[4 * s + 2];
        pk.u[3] = pw[4 * s + 3];
        acc = __builtin_amdgcn_mfma_f32_32x32x16_bf16(vf, pk.v8, acc, 0, 0, 0);
      }
      oacc[db] = acc;
    }
    __builtin_amdgcn_s_setprio(0);
  };

  STAGE(0, 0);
  int buf = 0;
  #pragma unroll 1
  for (int t = 0; t < nT; ++t) {
    if (t + 1 < nT) {
      STAGE(buf ^ 1, t + 1);
      asm volatile("s_waitcnt vmcnt(8)" ::: "memory");
    } else {
      asm volatile("s_waitcnt vmcnt(0)" ::: "memory");
    }
    __builtin_amdgcn_s_barrier();
    asm volatile("" ::: "memory");
    compute(buf);
    asm volatile("" ::: "memory");
    __builtin_amdgcn_s_barrier();
    buf ^= 1;
  }

  // ---- epilogue (R14/R15-verified layout) ----
  {
    float invl = 1.0f / lrun;
    float* ob = out + (size_t)(qt * 64 + (wv & 1) * 32 + l31) * (NHQ * HD) + h * HD + h8 * 4;
    #pragma unroll
    for (int db = 0; db < 4; ++db) {
      #pragma unroll
      for (int rq = 0; rq < 4; ++rq) {
        f32x4 vv;
        vv[0] = oacc[db][4 * rq + 0] * invl;
        vv[1] = oacc[db][4 * rq + 1] * invl;
        vv[2] = oacc[db][4 * rq + 2] * invl;
        vv[3] = oacc[db][4 * rq + 3] * invl;
        *(f32x4*)(ob + db * 32 + rq * 8) = vv;
      }
    }
  }
}

// ---------------- fallback (round-1 kernel, no ws needed) ----------------
__global__ __launch_bounds__(256) void attn_v1(
    const float* __restrict__ q,
    const float* __restrict__ k,
    const float* __restrict__ v,
    float* __restrict__ out)
{
  __shared__ unsigned short Ks[64 * 128];
  __shared__ unsigned short Vt[128 * 64];
  __shared__ unsigned short Psl[4][16 * 64];

  const int tid  = threadIdx.x;
  const int lane = tid & 63;
  const int wv   = tid >> 6;
  const int bx   = blockIdx.x;
  const int h    = bx & 31;
  const int qt   = (SEQL / 64 - 1) - (bx >> 5);
  const int q0   = qt * 64;
  const int hkv  = h >> 2;
  const int l15 = lane & 15;
  const int lhi = lane >> 4;
  const float qscale = 0.08838834764831845f * 1.4426950408889634f;

  bf16x8 qf[4];
  {
    const float* qbase = q + (size_t)(q0 + wv * 16 + l15) * (NHQ * HD) + h * HD + lhi * 8;
    #pragma unroll
    for (int c = 0; c < 4; ++c) {
      const float* p8 = qbase + c * 32;
      f32x4 a = *(const f32x4*)p8;
      f32x4 b = *(const f32x4*)(p8 + 4);
      bf16x8 r;
      r[0] = (short)f2bf(a[0] * qscale); r[1] = (short)f2bf(a[1] * qscale);
      r[2] = (short)f2bf(a[2] * qscale); r[3] = (short)f2bf(a[3] * qscale);
      r[4] = (short)f2bf(b[0] * qscale); r[5] = (short)f2bf(b[1] * qscale);
      r[6] = (short)f2bf(b[2] * qscale); r[7] = (short)f2bf(b[3] * qscale);
      qf[c] = r;
    }
  }
  f32x4 oacc[8];
  #pragma unroll
  for (int i = 0; i < 8; ++i) oacc[i] = (f32x4){0.f, 0.f, 0.f, 0.f};
  float mrun[4], lrun[4];
  #pragma unroll
  for (int r = 0; r < 4; ++r) { mrun[r] = -1e30f; lrun[r] = 0.f; }
  const int ntiles = ((q0 >> 7) + 1) * 2;
  for (int t = 0; t < ntiles; ++t) {
    const int kv0 = t * 64;
    __syncthreads();
    #pragma unroll
    for (int it = 0; it < 8; ++it) {
      int c = it * 256 + tid;
      int row = c >> 5;
      int dc = (c & 31) << 2;
      f32x4 x = *(const f32x4*)(k + (size_t)(kv0 + row) * (NHKV * HD) + hkv * HD + dc);
      u16x4 y;
      y[0] = f2bf(x[0]); y[1] = f2bf(x[1]); y[2] = f2bf(x[2]); y[3] = f2bf(x[3]);
      int idx = (row * HD + dc) ^ ((row & 7) << 3);
      *(u16x4*)(&Ks[idx]) = y;
    }
    {
      int row = tid >> 2;
      int db = (tid & 3) << 5;
      const float* vbase = v + (size_t)(kv0 + row) * (NHKV * HD) + hkv * HD + db;
      #pragma unroll
      for (int it = 0; it < 8; ++it) {
        f32x4 x = *(const f32x4*)(vbase + it * 4);
        int d0 = db + it * 4;
        #pragma unroll
        for (int j = 0; j < 4; ++j) {
          int d = d0 + j;
          int idx = (d * 64 + row) ^ ((d & 7) << 3);
          Vt[idx] = f2bf(x[j]);
        }
      }
    }
    __syncthreads();
    f32x4 sacc[4];
    #pragma unroll
    for (int sub = 0; sub < 4; ++sub) {
      f32x4 acc = (f32x4){0.f, 0.f, 0.f, 0.f};
      #pragma unroll
      for (int c = 0; c < 4; ++c) {
        int row = sub * 16 + l15;
        int idx = (row * HD + c * 32 + lhi * 8) ^ ((row & 7) << 3);
        bf16x8 kf = *(const bf16x8*)(&Ks[idx]);
        acc = __builtin_amdgcn_mfma_f32_16x16x32_bf16(qf[c], kf, acc, 0, 0, 0);
      }
      sacc[sub] = acc;
    }
    float corr[4];
    #pragma unroll
    for (int r = 0; r < 4; ++r) {
      float mt = fmaxf(fmaxf(sacc[0][r], sacc[1][r]), fmaxf(sacc[2][r], sacc[3][r]));
      #pragma unroll
      for (int off = 1; off < 16; off <<= 1) mt = fmaxf(mt, __shfl_xor(mt, off));
      float mnew = fmaxf(mrun[r], mt);
      corr[r] = exp2f(mrun[r] - mnew);
      mrun[r] = mnew;
      float p0 = exp2f(sacc[0][r] - mnew);
      float p1 = exp2f(sacc[1][r] - mnew);
      float p2 = exp2f(sacc[2][r] - mnew);
      float p3 = exp2f(sacc[3][r] - mnew);
      int qr = (lhi << 2) + r;
      int swz = (qr & 7) << 3;
      int bq = qr * 64;
      Psl[wv][(bq + 0  + l15) ^ swz] = f2bf(p0);
      Psl[wv][(bq + 16 + l15) ^ swz] = f2bf(p1);
      Psl[wv][(bq + 32 + l15) ^ swz] = f2bf(p2);
      Psl[wv][(bq + 48 + l15) ^ swz] = f2bf(p3);
      float ts = p0 + p1 + p2 + p3;
      #pragma unroll
      for (int off = 1; off < 16; off <<= 1) ts += __shfl_xor(ts, off);
      lrun[r] = lrun[r] * corr[r] + ts;
    }
    #pragma unroll
    for (int dsub = 0; dsub < 8; ++dsub) {
      f32x4 o = oacc[dsub];
      o[0] *= corr[0]; o[1] *= corr[1]; o[2] *= corr[2]; o[3] *= corr[3];
      oacc[dsub] = o;
    }
    #pragma unroll
    for (int kc = 0; kc < 2; ++kc) {
      int pidx = (l15 * 64 + kc * 32 + lhi * 8) ^ ((l15 & 7) << 3);
      bf16x8 pf = *(const bf16x8*)(&Psl[wv][pidx]);
      #pragma unroll
      for (int dsub = 0; dsub < 8; ++dsub) {
        int d = dsub * 16 + l15;
        int vidx = (d * 64 + kc * 32 + lhi * 8) ^ ((d & 7) << 3);
        bf16x8 vf = *(const bf16x8*)(&Vt[vidx]);
        oacc[dsub] = __builtin_amdgcn_mfma_f32_16x16x32_bf16(pf, vf, oacc[dsub], 0, 0, 0);
      }
    }
  }
  float inv[4];
  #pragma unroll
  for (int r = 0; r < 4; ++r) inv[r] = 1.0f / lrun[r];
  float* obase = out + (size_t)(q0 + wv * 16 + (lhi << 2)) * (NHQ * HD) + h * HD + l15;
  #pragma unroll
  for (int dsub = 0; dsub < 8; ++dsub) {
    #pragma unroll
    for (int r = 0; r < 4; ++r) {
      obase[(size_t)r * (NHQ * HD) + dsub * 16] = oacc[dsub][r] * inv[r];
    }
  }
}

extern "C" void kernel_launch(void* const* d_in, const int* in_sizes, int n_in,
                              void* d_out, int out_size, void* d_ws, size_t ws_size,
                              hipStream_t stream) {
  const float* q = (const float*)d_in[0];
  const float* k = (const float*)d_in[1];
  const float* v = (const float*)d_in[2];
  float* out = (float*)d_out;
  const size_t prepNeed = (size_t)8 * 1024 * 1024 + 512;
  if (ws_size >= prepNeed) {
    unsigned short* kws = (unsigned short*)d_ws;
    unsigned short* vws = kws + (size_t)4 * 1024 * 1024 / 2;
    prep_k<<<1024, 256, 0, stream>>>(k, kws);
    prep_v<<<1024, 256, 0, stream>>>(v, vws);
    attn_fwd16<<<512, 256, 0, stream>>>(q, kws, vws, out);
  } else {
    attn_v1<<<1024, 256, 0, stream>>>(q, k, v, out);
  }
}

// Round 17
// 82.623 us; speedup vs baseline: 1.1844x; 1.1844x over previous
//
#include <hip/hip_runtime.h>
#include <hip/hip_bf16.h>

#define SEQL  2048
#define NHQ   32
#define NHKV  8
#define HD    128

typedef __attribute__((ext_vector_type(4))) float          f32x4;
typedef __attribute__((ext_vector_type(8))) short          bf16x8;
typedef __attribute__((ext_vector_type(4))) unsigned short u16x4;
typedef __attribute__((ext_vector_type(8))) unsigned short u16x8;

__device__ __forceinline__ unsigned short f2bf(float f) {
  union { float f; unsigned u; } v; v.f = f;
  unsigned u = v.u;
  return (unsigned short)((u + 0x7fffu + ((u >> 16) & 1u)) >> 16);
}

__device__ __forceinline__ unsigned cvtpk_bf16(float lo, float hi) {
  unsigned r;
  asm("v_cvt_pk_bf16_f32 %0, %1, %2" : "=v"(r) : "v"(lo), "v"(hi));
  return r;
}

__device__ __forceinline__ void gload16(const void* g, void* l) {
  __builtin_amdgcn_global_load_lds(
      (const __attribute__((address_space(1))) unsigned int*)g,
      (__attribute__((address_space(3))) unsigned int*)l, 16, 0, 0);
}

// ---------------- prepass (merged K+V, per-thread code verified R2-R13) ----------------
// K image: [hkv][kvtile(32)][8192 hw], element (r,d) at (r*128+d)^((r&7)<<3)
// V image: [hkv][kvtile(32)][8192 hw], V^T with kv order permuted so the PV MFMA's
//          B-operand is the packed-in-register P (zero-shuffle PV, verified R8):
//          pos (d*64 + g*32 + lhi*8 + j)^((d&7)<<3) = V[tile*64 + g*32 + 4*lhi + 8*(j>>2) + (j&3)][d]
__global__ __launch_bounds__(256) void prep_kv(const float* __restrict__ k,
                                               const float* __restrict__ v,
                                               unsigned short* __restrict__ kws,
                                               unsigned short* __restrict__ vws) {
  int bx = blockIdx.x;
  if (bx < 1024) {
    int t = bx * 256 + threadIdx.x;
    int s   = t >> 7;
    int col = (t & 127) << 3;
    int hkv = col >> 7;
    int d0  = col & 127;
    const float* src = k + (size_t)s * (NHKV * HD) + col;
    f32x4 a = *(const f32x4*)src;
    f32x4 b = *(const f32x4*)(src + 4);
    u16x8 r;
    r[0] = f2bf(a[0]); r[1] = f2bf(a[1]); r[2] = f2bf(a[2]); r[3] = f2bf(a[3]);
    r[4] = f2bf(b[0]); r[5] = f2bf(b[1]); r[6] = f2bf(b[2]); r[7] = f2bf(b[3]);
    int tile = s >> 6, rr = s & 63;
    int idx = (rr * 128 + d0) ^ ((rr & 7) << 3);
    *(u16x8*)(kws + (((size_t)(hkv * 32 + tile)) << 13) + idx) = r;
  } else {
    int t = (bx - 1024) * 256 + threadIdx.x;
    int d    = t & 127;
    int hkv  = (t >> 7) & 7;
    int rest = t >> 10;            // 0..255
    int tile = rest >> 3;          // 0..31
    int g    = (rest >> 2) & 1;
    int lhi  = rest & 3;
    int s0   = tile * 64 + g * 32 + lhi * 4;
    const float* src = v + (size_t)s0 * (NHKV * HD) + hkv * HD + d;
    u16x8 r;
    #pragma unroll
    for (int j = 0; j < 8; ++j) {
      int soff = ((j >> 2) << 4) + (j & 3);
      r[j] = f2bf(src[(size_t)soff * (NHKV * HD)]);
    }
    int idx = (d * 64 + g * 32 + lhi * 8) ^ ((d & 7) << 3);
    *(u16x8*)(vws + (((size_t)(hkv * 32 + tile)) << 13) + idx) = r;
  }
}

// ---- main (v17 == verified R11, best at 85.6us): 4 waves x 16 q-rows,          ----
// ---- chunk pair (pr, 31-pr) = 34 tiles, K+V dbuf LDS + vmcnt(8), P packed in   ----
// ---- registers (zero-shuffle PV), V fragments hoisted above softmax.           ----
// LDS = 2x16K (K) + 2x16K (V) = 65536 B -> 2 blocks/CU, 8 waves/CU.
__global__ __launch_bounds__(256, 2) void attn_fwd17(
    const float* __restrict__ q,
    const unsigned short* __restrict__ kws,
    const unsigned short* __restrict__ vws,
    float* __restrict__ out)
{
  __shared__ unsigned short Kb[2][8192];
  __shared__ unsigned short Vb[2][8192];

  const int tid  = threadIdx.x;
  const int lane = tid & 63;
  const int wv   = tid >> 6;           // 0..3
  const int l15  = lane & 15;
  const int lhi  = lane >> 4;          // 0..3
  const int swzK = (l15 & 7) << 3;     // halfword-index XOR for K/V tiles

  const int bx   = blockIdx.x;
  const int hkv  = bx & 7;             // XCD-affine kv head
  const int h    = hkv * 4 + ((bx >> 3) & 3);
  const int pr   = bx >> 5;            // 0..15
  const int qtA  = pr, qtB = 31 - pr;  // 64-row chunks; nA+nB == 34 for all pr
  const int nA   = ((qtA >> 1) + 1) * 2;
  const int T    = 34;

  const float qscale = 0.08838834764831845f * 1.4426950408889634f;
  const float THR = 11.5f;             // defer-max threshold (log2 domain)

  const unsigned short* ktiles = kws + (((size_t)hkv * 32) << 13);
  const unsigned short* vtiles = vws + (((size_t)hkv * 32) << 13);

  bf16x8 qf[4];
  f32x4 oacc[8];
  float mrun, lrun;

  auto loadQ = [&](int qt) {
    const float* qbase = q + (size_t)(qt * 64 + wv * 16 + l15) * (NHQ * HD) + h * HD + lhi * 8;
    #pragma unroll
    for (int c = 0; c < 4; ++c) {
      f32x4 a = *(const f32x4*)(qbase + c * 32);
      f32x4 b = *(const f32x4*)(qbase + c * 32 + 4);
      bf16x8 r;
      r[0] = (short)f2bf(a[0] * qscale);
      r[1] = (short)f2bf(a[1] * qscale);
      r[2] = (short)f2bf(a[2] * qscale);
      r[3] = (short)f2bf(a[3] * qscale);
      r[4] = (short)f2bf(b[0] * qscale);
      r[5] = (short)f2bf(b[1] * qscale);
      r[6] = (short)f2bf(b[2] * qscale);
      r[7] = (short)f2bf(b[3] * qscale);
      qf[c] = r;
    }
  };

  auto resetAcc = [&]() {
    #pragma unroll
    for (int i = 0; i < 8; ++i) oacc[i] = (f32x4){0.f, 0.f, 0.f, 0.f};
    mrun = -1e30f; lrun = 0.f;
  };

  auto epilogue = [&](int qt) {
    float invl = 1.0f / lrun;
    float* ob = out + (size_t)(qt * 64 + wv * 16 + l15) * (NHQ * HD) + h * HD + lhi * 4;
    #pragma unroll
    for (int dsub = 0; dsub < 8; ++dsub)
      *(f32x4*)(ob + dsub * 16) = oacc[dsub] * invl;
  };

  auto STAGE = [&](int b, int kvt) {
    const char* gk = (const char*)(ktiles + ((size_t)kvt << 13));
    const char* gv = (const char*)(vtiles + ((size_t)kvt << 13));
    char* lk = (char*)&Kb[b][0];
    char* lv = (char*)&Vb[b][0];
    #pragma unroll
    for (int i = 0; i < 4; ++i) {
      const int off = wv * 4096 + i * 1024;
      gload16(gk + off + lane * 16, lk + off);
      gload16(gv + off + lane * 16, lv + off);
    }
  };

  auto compute = [&](int b) {
    // ---- S^T = K Q^T (lane holds 16 kv values for its q-row l15) ----
    f32x4 sa[4];
    __builtin_amdgcn_s_setprio(1);
    #pragma unroll
    for (int sub = 0; sub < 4; ++sub) {
      f32x4 acc = (f32x4){0.f, 0.f, 0.f, 0.f};
      const int row = sub * 16 + l15;
      #pragma unroll
      for (int c = 0; c < 4; ++c) {
        bf16x8 kf = *(const bf16x8*)(&Kb[b][(row * 128 + c * 32 + lhi * 8) ^ swzK]);
        acc = __builtin_amdgcn_mfma_f32_16x16x32_bf16(kf, qf[c], acc, 0, 0, 0);
      }
      sa[sub] = acc;
    }
    __builtin_amdgcn_s_setprio(0);
    // ---- HOIST: issue all V-fragment reads now; latency drains under softmax ----
    bf16x8 vr[2][8];
    #pragma unroll
    for (int kc = 0; kc < 2; ++kc)
      #pragma unroll
      for (int dsub = 0; dsub < 8; ++dsub) {
        const int d = dsub * 16 + l15;
        vr[kc][dsub] = *(const bf16x8*)(&Vb[b][(d * 64 + kc * 32 + lhi * 8) ^ swzK]);
      }
    // ---- row max: balanced tree + 2 shuffles ----
    float m0 = fmaxf(fmaxf(sa[0][0], sa[0][1]), fmaxf(sa[0][2], sa[0][3]));
    float m1 = fmaxf(fmaxf(sa[1][0], sa[1][1]), fmaxf(sa[1][2], sa[1][3]));
    float m2 = fmaxf(fmaxf(sa[2][0], sa[2][1]), fmaxf(sa[2][2], sa[2][3]));
    float m3 = fmaxf(fmaxf(sa[3][0], sa[3][1]), fmaxf(sa[3][2], sa[3][3]));
    float mt = fmaxf(fmaxf(m0, m1), fmaxf(m2, m3));
    mt = fmaxf(mt, __shfl_xor(mt, 16));
    mt = fmaxf(mt, __shfl_xor(mt, 32));
    // ---- defer-max ----
    if (__any(mt > mrun + THR)) {
      float mn = fmaxf(mrun, mt);
      float c0 = exp2f(mrun - mn);
      mrun = mn; lrun *= c0;
      #pragma unroll
      for (int d = 0; d < 8; ++d) oacc[d] *= c0;
    }
    // ---- P = exp2(S - m), packed in REGISTERS ----
    unsigned pw[8];
    {
      float ts = 0.f;
      #pragma unroll
      for (int sub = 0; sub < 4; ++sub) {
        float p0 = exp2f(sa[sub][0] - mrun);
        float p1 = exp2f(sa[sub][1] - mrun);
        float p2 = exp2f(sa[sub][2] - mrun);
        float p3 = exp2f(sa[sub][3] - mrun);
        ts += (p0 + p1) + (p2 + p3);
        pw[2 * sub]     = cvtpk_bf16(p0, p1);
        pw[2 * sub + 1] = cvtpk_bf16(p2, p3);
      }
      ts += __shfl_xor(ts, 16);
      ts += __shfl_xor(ts, 32);
      lrun += ts;
    }
    // ---- O^T += V^T P^T: pure-register MFMA burst (V hoisted, P packed) ----
    __builtin_amdgcn_s_setprio(1);
    #pragma unroll
    for (int kc = 0; kc < 2; ++kc) {
      union { unsigned u[4]; bf16x8 v8; } pk;
      pk.u[0] = pw[4 * kc + 0];
      pk.u[1] = pw[4 * kc + 1];
      pk.u[2] = pw[4 * kc + 2];
      pk.u[3] = pw[4 * kc + 3];
      bf16x8 pf = pk.v8;
      #pragma unroll
      for (int dsub = 0; dsub < 8; ++dsub) {
        oacc[dsub] = __builtin_amdgcn_mfma_f32_16x16x32_bf16(vr[kc][dsub], pf, oacc[dsub], 0, 0, 0);
      }
    }
    __builtin_amdgcn_s_setprio(0);
  };

  loadQ(qtA);
  resetAcc();
  STAGE(0, 0);
  int buf = 0;
  for (int t = 0; t < T; ++t) {
    if (t == nA) { epilogue(qtA); loadQ(qtB); resetAcc(); }
    if (t + 1 < T) {
      const int p = t + 1;
      STAGE(buf ^ 1, (p < nA) ? p : p - nA);
      asm volatile("s_waitcnt vmcnt(8)" ::: "memory");
    } else {
      asm volatile("s_waitcnt vmcnt(0)" ::: "memory");
    }
    __builtin_amdgcn_s_barrier();
    asm volatile("" ::: "memory");
    compute(buf);
    asm volatile("" ::: "memory");
    __builtin_amdgcn_s_barrier();
    buf ^= 1;
  }
  epilogue(qtB);
}

// ---------------- fallback (round-1 kernel, no ws needed) ----------------
__global__ __launch_bounds__(256) void attn_v1(
    const float* __restrict__ q,
    const float* __restrict__ k,
    const float* __restrict__ v,
    float* __restrict__ out)
{
  __shared__ unsigned short Ks[64 * 128];
  __shared__ unsigned short Vt[128 * 64];
  __shared__ unsigned short Psl[4][16 * 64];

  const int tid  = threadIdx.x;
  const int lane = tid & 63;
  const int wv   = tid >> 6;
  const int bx   = blockIdx.x;
  const int h    = bx & 31;
  const int qt   = (SEQL / 64 - 1) - (bx >> 5);
  const int q0   = qt * 64;
  const int hkv  = h >> 2;
  const int l15 = lane & 15;
  const int lhi = lane >> 4;
  const float qscale = 0.08838834764831845f * 1.4426950408889634f;

  bf16x8 qf[4];
  {
    const float* qbase = q + (size_t)(q0 + wv * 16 + l15) * (NHQ * HD) + h * HD + lhi * 8;
    #pragma unroll
    for (int c = 0; c < 4; ++c) {
      const float* p8 = qbase + c * 32;
      f32x4 a = *(const f32x4*)p8;
      f32x4 b = *(const f32x4*)(p8 + 4);
      bf16x8 r;
      r[0] = (short)f2bf(a[0] * qscale); r[1] = (short)f2bf(a[1] * qscale);
      r[2] = (short)f2bf(a[2] * qscale); r[3] = (short)f2bf(a[3] * qscale);
      r[4] = (short)f2bf(b[0] * qscale); r[5] = (short)f2bf(b[1] * qscale);
      r[6] = (short)f2bf(b[2] * qscale); r[7] = (short)f2bf(b[3] * qscale);
      qf[c] = r;
    }
  }
  f32x4 oacc[8];
  #pragma unroll
  for (int i = 0; i < 8; ++i) oacc[i] = (f32x4){0.f, 0.f, 0.f, 0.f};
  float mrun[4], lrun[4];
  #pragma unroll
  for (int r = 0; r < 4; ++r) { mrun[r] = -1e30f; lrun[r] = 0.f; }
  const int ntiles = ((q0 >> 7) + 1) * 2;
  for (int t = 0; t < ntiles; ++t) {
    const int kv0 = t * 64;
    __syncthreads();
    #pragma unroll
    for (int it = 0; it < 8; ++it) {
      int c = it * 256 + tid;
      int row = c >> 5;
      int dc = (c & 31) << 2;
      f32x4 x = *(const f32x4*)(k + (size_t)(kv0 + row) * (NHKV * HD) + hkv * HD + dc);
      u16x4 y;
      y[0] = f2bf(x[0]); y[1] = f2bf(x[1]); y[2] = f2bf(x[2]); y[3] = f2bf(x[3]);
      int idx = (row * HD + dc) ^ ((row & 7) << 3);
      *(u16x4*)(&Ks[idx]) = y;
    }
    {
      int row = tid >> 2;
      int db = (tid & 3) << 5;
      const float* vbase = v + (size_t)(kv0 + row) * (NHKV * HD) + hkv * HD + db;
      #pragma unroll
      for (int it = 0; it < 8; ++it) {
        f32x4 x = *(const f32x4*)(vbase + it * 4);
        int d0 = db + it * 4;
        #pragma unroll
        for (int j = 0; j < 4; ++j) {
          int d = d0 + j;
          int idx = (d * 64 + row) ^ ((d & 7) << 3);
          Vt[idx] = f2bf(x[j]);
        }
      }
    }
    __syncthreads();
    f32x4 sacc[4];
    #pragma unroll
    for (int sub = 0; sub < 4; ++sub) {
      f32x4 acc = (f32x4){0.f, 0.f, 0.f, 0.f};
      #pragma unroll
      for (int c = 0; c < 4; ++c) {
        int row = sub * 16 + l15;
        int idx = (row * HD + c * 32 + lhi * 8) ^ ((row & 7) << 3);
        bf16x8 kf = *(const bf16x8*)(&Ks[idx]);
        acc = __builtin_amdgcn_mfma_f32_16x16x32_bf16(qf[c], kf, acc, 0, 0, 0);
      }
      sacc[sub] = acc;
    }
    float corr[4];
    #pragma unroll
    for (int r = 0; r < 4; ++r) {
      float mt = fmaxf(fmaxf(sacc[0][r], sacc[1][r]), fmaxf(sacc[2][r], sacc[3][r]));
      #pragma unroll
      for (int off = 1; off < 16; off <<= 1) mt = fmaxf(mt, __shfl_xor(mt, off));
      float mnew = fmaxf(mrun[r], mt);
      corr[r] = exp2f(mrun[r] - mnew);
      mrun[r] = mnew;
      float p0 = exp2f(sacc[0][r] - mnew);
      float p1 = exp2f(sacc[1][r] - mnew);
      float p2 = exp2f(sacc[2][r] - mnew);
      float p3 = exp2f(sacc[3][r] - mnew);
      int qr = (lhi << 2) + r;
      int swz = (qr & 7) << 3;
      int bq = qr * 64;
      Psl[wv][(bq + 0  + l15) ^ swz] = f2bf(p0);
      Psl[wv][(bq + 16 + l15) ^ swz] = f2bf(p1);
      Psl[wv][(bq + 32 + l15) ^ swz] = f2bf(p2);
      Psl[wv][(bq + 48 + l15) ^ swz] = f2bf(p3);
      float ts = p0 + p1 + p2 + p3;
      #pragma unroll
      for (int off = 1; off < 16; off <<= 1) ts += __shfl_xor(ts, off);
      lrun[r] = lrun[r] * corr[r] + ts;
    }
    #pragma unroll
    for (int dsub = 0; dsub < 8; ++dsub) {
      f32x4 o = oacc[dsub];
      o[0] *= corr[0]; o[1] *= corr[1]; o[2] *= corr[2]; o[3] *= corr[3];
      oacc[dsub] = o;
    }
    #pragma unroll
    for (int kc = 0; kc < 2; ++kc) {
      int pidx = (l15 * 64 + kc * 32 + lhi * 8) ^ ((l15 & 7) << 3);
      bf16x8 pf = *(const bf16x8*)(&Psl[wv][pidx]);
      #pragma unroll
      for (int dsub = 0; dsub < 8; ++dsub) {
        int d = dsub * 16 + l15;
        int vidx = (d * 64 + kc * 32 + lhi * 8) ^ ((d & 7) << 3);
        bf16x8 vf = *(const bf16x8*)(&Vt[vidx]);
        oacc[dsub] = __builtin_amdgcn_mfma_f32_16x16x32_bf16(pf, vf, oacc[dsub], 0, 0, 0);
      }
    }
  }
  float inv[4];
  #pragma unroll
  for (int r = 0; r < 4; ++r) inv[r] = 1.0f / lrun[r];
  float* obase = out + (size_t)(q0 + wv * 16 + (lhi << 2)) * (NHQ * HD) + h * HD + l15;
  #pragma unroll
  for (int dsub = 0; dsub < 8; ++dsub) {
    #pragma unroll
    for (int r = 0; r < 4; ++r) {
      obase[(size_t)r * (NHQ * HD) + dsub * 16] = oacc[dsub][r] * inv[r];
    }
  }
}

extern "C" void kernel_launch(void* const* d_in, const int* in_sizes, int n_in,
                              void* d_out, int out_size, void* d_ws, size_t ws_size,
                              hipStream_t stream) {
  const float* q = (const float*)d_in[0];
  const float* k = (const float*)d_in[1];
  const float* v = (const float*)d_in[2];
  float* out = (float*)d_out;
  const size_t prepNeed = (size_t)8 * 1024 * 1024 + 512;
  if (ws_size >= prepNeed) {
    unsigned short* kws = (unsigned short*)d_ws;
    unsigned short* vws = kws + (size_t)4 * 1024 * 1024 / 2;
    prep_kv<<<2048, 256, 0, stream>>>(k, v, kws, vws);
    attn_fwd17<<<512, 256, 0, stream>>>(q, kws, vws, out);
  } else {
    attn_v1<<<1024, 256, 0, stream>>>(q, k, v, out);
  }
}

// Round 18
// 82.154 us; speedup vs baseline: 1.1912x; 1.0057x over previous
//
#include <hip/hip_runtime.h>
#include <hip/hip_bf16.h>

#define SEQL  2048
#define NHQ   32
#define NHKV  8
#define HD    128

typedef __attribute__((ext_vector_type(4))) float          f32x4;
typedef __attribute__((ext_vector_type(8))) short          bf16x8;
typedef __attribute__((ext_vector_type(4))) unsigned short u16x4;
typedef __attribute__((ext_vector_type(8))) unsigned short u16x8;

__device__ __forceinline__ unsigned short f2bf(float f) {
  union { float f; unsigned u; } v; v.f = f;
  unsigned u = v.u;
  return (unsigned short)((u + 0x7fffu + ((u >> 16) & 1u)) >> 16);
}

__device__ __forceinline__ unsigned cvtpk_bf16(float lo, float hi) {
  unsigned r;
  asm("v_cvt_pk_bf16_f32 %0, %1, %2" : "=v"(r) : "v"(lo), "v"(hi));
  return r;
}

__device__ __forceinline__ void gload16(const void* g, void* l) {
  __builtin_amdgcn_global_load_lds(
      (const __attribute__((address_space(1))) unsigned int*)g,
      (__attribute__((address_space(3))) unsigned int*)l, 16, 0, 0);
}

// ---------------- prepass (merged K+V, verified R17) ----------------
// K image: [hkv][kvtile(32)][8192 hw], element (r,d) at (r*128+d)^((r&7)<<3)
// V image: [hkv][kvtile(32)][8192 hw], V^T with kv order permuted so the PV MFMA's
//          B-operand is the packed-in-register P (zero-shuffle PV, verified R8):
//          pos (d*64 + g*32 + lhi*8 + j)^((d&7)<<3) = V[tile*64 + g*32 + 4*lhi + 8*(j>>2) + (j&3)][d]
__global__ __launch_bounds__(256) void prep_kv(const float* __restrict__ k,
                                               const float* __restrict__ v,
                                               unsigned short* __restrict__ kws,
                                               unsigned short* __restrict__ vws) {
  int bx = blockIdx.x;
  if (bx < 1024) {
    int t = bx * 256 + threadIdx.x;
    int s   = t >> 7;
    int col = (t & 127) << 3;
    int hkv = col >> 7;
    int d0  = col & 127;
    const float* src = k + (size_t)s * (NHKV * HD) + col;
    f32x4 a = *(const f32x4*)src;
    f32x4 b = *(const f32x4*)(src + 4);
    u16x8 r;
    r[0] = f2bf(a[0]); r[1] = f2bf(a[1]); r[2] = f2bf(a[2]); r[3] = f2bf(a[3]);
    r[4] = f2bf(b[0]); r[5] = f2bf(b[1]); r[6] = f2bf(b[2]); r[7] = f2bf(b[3]);
    int tile = s >> 6, rr = s & 63;
    int idx = (rr * 128 + d0) ^ ((rr & 7) << 3);
    *(u16x8*)(kws + (((size_t)(hkv * 32 + tile)) << 13) + idx) = r;
  } else {
    int t = (bx - 1024) * 256 + threadIdx.x;
    int d    = t & 127;
    int hkv  = (t >> 7) & 7;
    int rest = t >> 10;            // 0..255
    int tile = rest >> 3;          // 0..31
    int g    = (rest >> 2) & 1;
    int lhi  = rest & 3;
    int s0   = tile * 64 + g * 32 + lhi * 4;
    const float* src = v + (size_t)s0 * (NHKV * HD) + hkv * HD + d;
    u16x8 r;
    #pragma unroll
    for (int j = 0; j < 8; ++j) {
      int soff = ((j >> 2) << 4) + (j & 3);
      r[j] = f2bf(src[(size_t)soff * (NHKV * HD)]);
    }
    int idx = (d * 64 + g * 32 + lhi * 8) ^ ((d & 7) << 3);
    *(u16x8*)(vws + (((size_t)(hkv * 32 + tile)) << 13) + idx) = r;
  }
}

// ---- main (v18 = R17 + qfB-preload + max3-shaped row max): 4 waves x 16 q-rows, ----
// ---- chunk pair (pr, 31-pr) = 34 tiles, K+V dbuf LDS + vmcnt(8), P packed in    ----
// ---- registers (zero-shuffle PV), V fragments hoisted above softmax.            ----
// LDS = 2x16K (K) + 2x16K (V) = 65536 B -> 2 blocks/CU, 8 waves/CU.
__global__ __launch_bounds__(256, 2) void attn_fwd18(
    const float* __restrict__ q,
    const unsigned short* __restrict__ kws,
    const unsigned short* __restrict__ vws,
    float* __restrict__ out)
{
  __shared__ unsigned short Kb[2][8192];
  __shared__ unsigned short Vb[2][8192];

  const int tid  = threadIdx.x;
  const int lane = tid & 63;
  const int wv   = tid >> 6;           // 0..3
  const int l15  = lane & 15;
  const int lhi  = lane >> 4;          // 0..3
  const int swzK = (l15 & 7) << 3;     // halfword-index XOR for K/V tiles

  const int bx   = blockIdx.x;
  const int hkv  = bx & 7;             // XCD-affine kv head
  const int h    = hkv * 4 + ((bx >> 3) & 3);
  const int pr   = bx >> 5;            // 0..15
  const int qtA  = pr, qtB = 31 - pr;  // 64-row chunks; nA+nB == 34 for all pr
  const int nA   = ((qtA >> 1) + 1) * 2;
  const int T    = 34;

  const float qscale = 0.08838834764831845f * 1.4426950408889634f;
  const float THR = 11.5f;             // defer-max threshold (log2 domain)

  const unsigned short* ktiles = kws + (((size_t)hkv * 32) << 13);
  const unsigned short* vtiles = vws + (((size_t)hkv * 32) << 13);

  bf16x8 qf[4], qfB[4];
  f32x4 oacc[8];
  float mrun, lrun;

  auto loadQinto = [&](int qt, bf16x8* dst) {
    const float* qbase = q + (size_t)(qt * 64 + wv * 16 + l15) * (NHQ * HD) + h * HD + lhi * 8;
    #pragma unroll
    for (int c = 0; c < 4; ++c) {
      f32x4 a = *(const f32x4*)(qbase + c * 32);
      f32x4 b = *(const f32x4*)(qbase + c * 32 + 4);
      bf16x8 r;
      r[0] = (short)f2bf(a[0] * qscale);
      r[1] = (short)f2bf(a[1] * qscale);
      r[2] = (short)f2bf(a[2] * qscale);
      r[3] = (short)f2bf(a[3] * qscale);
      r[4] = (short)f2bf(b[0] * qscale);
      r[5] = (short)f2bf(b[1] * qscale);
      r[6] = (short)f2bf(b[2] * qscale);
      r[7] = (short)f2bf(b[3] * qscale);
      dst[c] = r;
    }
  };

  auto resetAcc = [&]() {
    #pragma unroll
    for (int i = 0; i < 8; ++i) oacc[i] = (f32x4){0.f, 0.f, 0.f, 0.f};
    mrun = -1e30f; lrun = 0.f;
  };

  auto epilogue = [&](int qt) {
    float invl = 1.0f / lrun;
    float* ob = out + (size_t)(qt * 64 + wv * 16 + l15) * (NHQ * HD) + h * HD + lhi * 4;
    #pragma unroll
    for (int dsub = 0; dsub < 8; ++dsub)
      *(f32x4*)(ob + dsub * 16) = oacc[dsub] * invl;
  };

  auto STAGE = [&](int b, int kvt) {
    const char* gk = (const char*)(ktiles + ((size_t)kvt << 13));
    const char* gv = (const char*)(vtiles + ((size_t)kvt << 13));
    char* lk = (char*)&Kb[b][0];
    char* lv = (char*)&Vb[b][0];
    #pragma unroll
    for (int i = 0; i < 4; ++i) {
      const int off = wv * 4096 + i * 1024;
      gload16(gk + off + lane * 16, lk + off);
      gload16(gv + off + lane * 16, lv + off);
    }
  };

  auto compute = [&](int b) {
    // ---- S^T = K Q^T (lane holds 16 kv values for its q-row l15) ----
    f32x4 sa[4];
    __builtin_amdgcn_s_setprio(1);
    #pragma unroll
    for (int sub = 0; sub < 4; ++sub) {
      f32x4 acc = (f32x4){0.f, 0.f, 0.f, 0.f};
      const int row = sub * 16 + l15;
      #pragma unroll
      for (int c = 0; c < 4; ++c) {
        bf16x8 kf = *(const bf16x8*)(&Kb[b][(row * 128 + c * 32 + lhi * 8) ^ swzK]);
        acc = __builtin_amdgcn_mfma_f32_16x16x32_bf16(kf, qf[c], acc, 0, 0, 0);
      }
      sa[sub] = acc;
    }
    __builtin_amdgcn_s_setprio(0);
    // ---- HOIST: issue all V-fragment reads now; latency drains under softmax ----
    bf16x8 vr[2][8];
    #pragma unroll
    for (int kc = 0; kc < 2; ++kc)
      #pragma unroll
      for (int dsub = 0; dsub < 8; ++dsub) {
        const int d = dsub * 16 + l15;
        vr[kc][dsub] = *(const bf16x8*)(&Vb[b][(d * 64 + kc * 32 + lhi * 8) ^ swzK]);
      }
    // ---- row max: max3-shaped tree (v_max3_f32 fusable) + 2 shuffles ----
    float t0 = fmaxf(fmaxf(sa[0][0], sa[0][1]), sa[0][2]);
    float t1 = fmaxf(fmaxf(sa[0][3], sa[1][0]), sa[1][1]);
    float t2 = fmaxf(fmaxf(sa[1][2], sa[1][3]), sa[2][0]);
    float t3 = fmaxf(fmaxf(sa[2][1], sa[2][2]), sa[2][3]);
    float t4 = fmaxf(fmaxf(sa[3][0], sa[3][1]), sa[3][2]);
    float mt = fmaxf(fmaxf(fmaxf(t0, t1), t2),
                     fmaxf(fmaxf(t3, t4), sa[3][3]));
    mt = fmaxf(mt, __shfl_xor(mt, 16));
    mt = fmaxf(mt, __shfl_xor(mt, 32));
    // ---- defer-max ----
    if (__any(mt > mrun + THR)) {
      float mn = fmaxf(mrun, mt);
      float c0 = exp2f(mrun - mn);
      mrun = mn; lrun *= c0;
      #pragma unroll
      for (int d = 0; d < 8; ++d) oacc[d] *= c0;
    }
    // ---- P = exp2(S - m), packed in REGISTERS ----
    unsigned pw[8];
    {
      float ts = 0.f;
      #pragma unroll
      for (int sub = 0; sub < 4; ++sub) {
        float p0 = exp2f(sa[sub][0] - mrun);
        float p1 = exp2f(sa[sub][1] - mrun);
        float p2 = exp2f(sa[sub][2] - mrun);
        float p3 = exp2f(sa[sub][3] - mrun);
        ts += (p0 + p1) + (p2 + p3);
        pw[2 * sub]     = cvtpk_bf16(p0, p1);
        pw[2 * sub + 1] = cvtpk_bf16(p2, p3);
      }
      ts += __shfl_xor(ts, 16);
      ts += __shfl_xor(ts, 32);
      lrun += ts;
    }
    // ---- O^T += V^T P^T: pure-register MFMA burst (V hoisted, P packed) ----
    __builtin_amdgcn_s_setprio(1);
    #pragma unroll
    for (int kc = 0; kc < 2; ++kc) {
      union { unsigned u[4]; bf16x8 v8; } pk;
      pk.u[0] = pw[4 * kc + 0];
      pk.u[1] = pw[4 * kc + 1];
      pk.u[2] = pw[4 * kc + 2];
      pk.u[3] = pw[4 * kc + 3];
      bf16x8 pf = pk.v8;
      #pragma unroll
      for (int dsub = 0; dsub < 8; ++dsub) {
        oacc[dsub] = __builtin_amdgcn_mfma_f32_16x16x32_bf16(vr[kc][dsub], pf, oacc[dsub], 0, 0, 0);
      }
    }
    __builtin_amdgcn_s_setprio(0);
  };

  loadQinto(qtA, qf);
  loadQinto(qtB, qfB);   // resident for phase 2; no mid-loop global loads
  resetAcc();
  STAGE(0, 0);
  int buf = 0;
  for (int t = 0; t < T; ++t) {
    if (t == nA) {
      epilogue(qtA);
      #pragma unroll
      for (int c = 0; c < 4; ++c) qf[c] = qfB[c];   // 4 vector moves, no loads
      resetAcc();
    }
    if (t + 1 < T) {
      const int p = t + 1;
      STAGE(buf ^ 1, (p < nA) ? p : p - nA);
      asm volatile("s_waitcnt vmcnt(8)" ::: "memory");
    } else {
      asm volatile("s_waitcnt vmcnt(0)" ::: "memory");
    }
    __builtin_amdgcn_s_barrier();
    asm volatile("" ::: "memory");
    compute(buf);
    asm volatile("" ::: "memory");
    __builtin_amdgcn_s_barrier();
    buf ^= 1;
  }
  epilogue(qtB);
}

// ---------------- fallback (round-1 kernel, no ws needed) ----------------
__global__ __launch_bounds__(256) void attn_v1(
    const float* __restrict__ q,
    const float* __restrict__ k,
    const float* __restrict__ v,
    float* __restrict__ out)
{
  __shared__ unsigned short Ks[64 * 128];
  __shared__ unsigned short Vt[128 * 64];
  __shared__ unsigned short Psl[4][16 * 64];

  const int tid  = threadIdx.x;
  const int lane = tid & 63;
  const int wv   = tid >> 6;
  const int bx   = blockIdx.x;
  const int h    = bx & 31;
  const int qt   = (SEQL / 64 - 1) - (bx >> 5);
  const int q0   = qt * 64;
  const int hkv  = h >> 2;
  const int l15 = lane & 15;
  const int lhi = lane >> 4;
  const float qscale = 0.08838834764831845f * 1.4426950408889634f;

  bf16x8 qf[4];
  {
    const float* qbase = q + (size_t)(q0 + wv * 16 + l15) * (NHQ * HD) + h * HD + lhi * 8;
    #pragma unroll
    for (int c = 0; c < 4; ++c) {
      const float* p8 = qbase + c * 32;
      f32x4 a = *(const f32x4*)p8;
      f32x4 b = *(const f32x4*)(p8 + 4);
      bf16x8 r;
      r[0] = (short)f2bf(a[0] * qscale); r[1] = (short)f2bf(a[1] * qscale);
      r[2] = (short)f2bf(a[2] * qscale); r[3] = (short)f2bf(a[3] * qscale);
      r[4] = (short)f2bf(b[0] * qscale); r[5] = (short)f2bf(b[1] * qscale);
      r[6] = (short)f2bf(b[2] * qscale); r[7] = (short)f2bf(b[3] * qscale);
      qf[c] = r;
    }
  }
  f32x4 oacc[8];
  #pragma unroll
  for (int i = 0; i < 8; ++i) oacc[i] = (f32x4){0.f, 0.f, 0.f, 0.f};
  float mrun[4], lrun[4];
  #pragma unroll
  for (int r = 0; r < 4; ++r) { mrun[r] = -1e30f; lrun[r] = 0.f; }
  const int ntiles = ((q0 >> 7) + 1) * 2;
  for (int t = 0; t < ntiles; ++t) {
    const int kv0 = t * 64;
    __syncthreads();
    #pragma unroll
    for (int it = 0; it < 8; ++it) {
      int c = it * 256 + tid;
      int row = c >> 5;
      int dc = (c & 31) << 2;
      f32x4 x = *(const f32x4*)(k + (size_t)(kv0 + row) * (NHKV * HD) + hkv * HD + dc);
      u16x4 y;
      y[0] = f2bf(x[0]); y[1] = f2bf(x[1]); y[2] = f2bf(x[2]); y[3] = f2bf(x[3]);
      int idx = (row * HD + dc) ^ ((row & 7) << 3);
      *(u16x4*)(&Ks[idx]) = y;
    }
    {
      int row = tid >> 2;
      int db = (tid & 3) << 5;
      const float* vbase = v + (size_t)(kv0 + row) * (NHKV * HD) + hkv * HD + db;
      #pragma unroll
      for (int it = 0; it < 8; ++it) {
        f32x4 x = *(const f32x4*)(vbase + it * 4);
        int d0 = db + it * 4;
        #pragma unroll
        for (int j = 0; j < 4; ++j) {
          int d = d0 + j;
          int idx = (d * 64 + row) ^ ((d & 7) << 3);
          Vt[idx] = f2bf(x[j]);
        }
      }
    }
    __syncthreads();
    f32x4 sacc[4];
    #pragma unroll
    for (int sub = 0; sub < 4; ++sub) {
      f32x4 acc = (f32x4){0.f, 0.f, 0.f, 0.f};
      #pragma unroll
      for (int c = 0; c < 4; ++c) {
        int row = sub * 16 + l15;
        int idx = (row * HD + c * 32 + lhi * 8) ^ ((row & 7) << 3);
        bf16x8 kf = *(const bf16x8*)(&Ks[idx]);
        acc = __builtin_amdgcn_mfma_f32_16x16x32_bf16(qf[c], kf, acc, 0, 0, 0);
      }
      sacc[sub] = acc;
    }
    float corr[4];
    #pragma unroll
    for (int r = 0; r < 4; ++r) {
      float mt = fmaxf(fmaxf(sacc[0][r], sacc[1][r]), fmaxf(sacc[2][r], sacc[3][r]));
      #pragma unroll
      for (int off = 1; off < 16; off <<= 1) mt = fmaxf(mt, __shfl_xor(mt, off));
      float mnew = fmaxf(mrun[r], mt);
      corr[r] = exp2f(mrun[r] - mnew);
      mrun[r] = mnew;
      float p0 = exp2f(sacc[0][r] - mnew);
      float p1 = exp2f(sacc[1][r] - mnew);
      float p2 = exp2f(sacc[2][r] - mnew);
      float p3 = exp2f(sacc[3][r] - mnew);
      int qr = (lhi << 2) + r;
      int swz = (qr & 7) << 3;
      int bq = qr * 64;
      Psl[wv][(bq + 0  + l15) ^ swz] = f2bf(p0);
      Psl[wv][(bq + 16 + l15) ^ swz] = f2bf(p1);
      Psl[wv][(bq + 32 + l15) ^ swz] = f2bf(p2);
      Psl[wv][(bq + 48 + l15) ^ swz] = f2bf(p3);
      float ts = p0 + p1 + p2 + p3;
      #pragma unroll
      for (int off = 1; off < 16; off <<= 1) ts += __shfl_xor(ts, off);
      lrun[r] = lrun[r] * corr[r] + ts;
    }
    #pragma unroll
    for (int dsub = 0; dsub < 8; ++dsub) {
      f32x4 o = oacc[dsub];
      o[0] *= corr[0]; o[1] *= corr[1]; o[2] *= corr[2]; o[3] *= corr[3];
      oacc[dsub] = o;
    }
    #pragma unroll
    for (int kc = 0; kc < 2; ++kc) {
      int pidx = (l15 * 64 + kc * 32 + lhi * 8) ^ ((l15 & 7) << 3);
      bf16x8 pf = *(const bf16x8*)(&Psl[wv][pidx]);
      #pragma unroll
      for (int dsub = 0; dsub < 8; ++dsub) {
        int d = dsub * 16 + l15;
        int vidx = (d * 64 + kc * 32 + lhi * 8) ^ ((d & 7) << 3);
        bf16x8 vf = *(const bf16x8*)(&Vt[vidx]);
        oacc[dsub] = __builtin_amdgcn_mfma_f32_16x16x32_bf16(pf, vf, oacc[dsub], 0, 0, 0);
      }
    }
  }
  float inv[4];
  #pragma unroll
  for (int r = 0; r < 4; ++r) inv[r] = 1.0f / lrun[r];
  float* obase = out + (size_t)(q0 + wv * 16 + (lhi << 2)) * (NHQ * HD) + h * HD + l15;
  #pragma unroll
  for (int dsub = 0; dsub < 8; ++dsub) {
    #pragma unroll
    for (int r = 0; r < 4; ++r) {
      obase[(size_t)r * (NHQ * HD) + dsub * 16] = oacc[dsub][r] * inv[r];
    }
  }
}

extern "C" void kernel_launch(void* const* d_in, const int* in_sizes, int n_in,
                              void* d_out, int out_size, void* d_ws, size_t ws_size,
                              hipStream_t stream) {
  const float* q = (const float*)d_in[0];
  const float* k = (const float*)d_in[1];
  const float* v = (const float*)d_in[2];
  float* out = (float*)d_out;
  const size_t prepNeed = (size_t)8 * 1024 * 1024 + 512;
  if (ws_size >= prepNeed) {
    unsigned short* kws = (unsigned short*)d_ws;
    unsigned short* vws = kws + (size_t)4 * 1024 * 1024 / 2;
    prep_kv<<<2048, 256, 0, stream>>>(k, v, kws, vws);
    attn_fwd18<<<512, 256, 0, stream>>>(q, kws, vws, out);
  } else {
    attn_v1<<<1024, 256, 0, stream>>>(q, k, v, out);
  }
}